// Round 6
// baseline (305.601 us; speedup 1.0000x reference)
//
#include <hip/hip_runtime.h>

// x: [8, 1, 160, 160, 160] fp32; log_sigma: [3] fp32; out: scalar fp32.
// loss = -(sum over 3816 (axis,b,pair) of exp(-sq/(2*sigma_axis^2))) / 3816.
//
// R12: TAIL COLLAPSE. R10's probe: diff3=65us, fill=75us (fixed), leaving
// tail+gaps=56us. R11 (MLP hoist) nulled -> cold-read ~2.9 TB/s is not
// source-schedulable; revert to exact R6 body (VGPR=68, best measured).
// The 56us tail is re-attributed to reduce_kernel itself: 60 blocks x 64
// threads = 15 threads/CU, each W-thread doing 160 line-granular strided
// loads (stride 800B) from OTHER XCDs' L2s (~203K cross-XCD misses, no
// parallelism to hide ~600ns each). Fix: delete the per-block ws slots +
// reduce/final entirely:
//   zero_kernel (1 blk): zero acc[3816] + cnt in ws.
//   diff3 flush: atomicAdd per-key partials (197/blk, device-scope,
//     spread over kernel lifetime; hottest cell 160 adds) into acc.
//   last block (ticket via atomic cnt): reads 3816 floats (agent-scope
//     atomic loads, 12/thread), computes exp(val*f), reduces, writes out.
// Predicted: total 196 -> ~150-160; diff3 ~67-70us; absmax stays 0.

constexpr int Wd4 = 40;              // float4 per row
constexpr int SLICE4 = 6400;         // float4 per slice
constexpr long BSTR4 = 160L * 6400;  // float4 per batch
constexpr int NB = 8;
constexpr int NPAIR = 159;
constexpr int NKEY = 3 * NB * NPAIR;   // 3816
constexpr int PBATCH = NB * NPAIR;     // 1272 keys per axis
constexpr int NBLK = NB * 160;         // 8 b x 32 d-segs x 5 h-chunks = 1280
constexpr int NZ = NKEY + 1;           // acc[3816] + cnt

__device__ __forceinline__ float sq4(const float4& a, const float4& c) {
    float e0 = a.x - c.x, e1 = a.y - c.y, e2 = a.z - c.z, e3 = a.w - c.w;
    return e0 * e0 + e1 * e1 + e2 * e2 + e3 * e3;
}

__global__ __launch_bounds__(512) void zero_kernel(float* __restrict__ ws) {
    for (int i = threadIdx.x; i < NZ; i += 512) ws[i] = 0.f;
}

// 1280 blocks x 320 threads. bid -> (b, ds 0..31, hc 0..4). Thread: c4=t%40,
// rp=t/40 owns rows h0+4rp+{0..3}. Slices d0..d0+4 owned, d0+5 halo (v only).
__global__ __launch_bounds__(320) void diff3_kernel(const float* __restrict__ x,
                                                    const float* __restrict__ log_sigma,
                                                    float* __restrict__ ws,
                                                    float* __restrict__ out) {
    __shared__ float lds[1504];  // H: [0..1311] 32 keys*41; D: [1472..1496]; W reuses [0..1439]
    __shared__ int sTicket;

    const int t = threadIdx.x;
    const int bid = blockIdx.x;
    const int b = bid / 160;
    const int r2 = bid % 160;
    const int ds = r2 / 5;     // d-segment, d0 = 5*ds
    const int hc = r2 % 5;     // h-chunk,  h0 = 32*hc
    const int d0 = ds * 5, h0 = hc * 32;
    const bool lastSeg = (ds == 31);

    const int c4 = t % 40;
    const int rp = t / 40;                  // 0..7
    const int lane = t & 63;
    const int wv = t >> 6;                  // wave 0..4
    const bool hOK = !(hc == 4 && rp == 7); // row h0+4rp+4 <= 159
    const bool sOK = (c4 < 39);
    const bool fixB = (lane == 63) && sOK;  // shfl partner in next wave -> load

    const float4* base = (const float4*)x + (size_t)b * BSTR4 + (size_t)d0 * SLICE4
                       + (size_t)(h0 + 4 * rp) * Wd4 + c4;

    float aW[4] = {0.f, 0.f, 0.f, 0.f};
    float aH[4] = {0.f, 0.f, 0.f, 0.f};
    float aD[5] = {0.f, 0.f, 0.f, 0.f, 0.f};
    float4 p0, p1, p2, p3;

#pragma unroll
    for (int it = 0; it < 5; ++it) {
        const float4* sp = base + it * SLICE4;
        const float4 v0 = sp[0];
        const float4 v1 = sp[Wd4];
        const float4 v2 = sp[2 * Wd4];
        const float4 v3 = sp[3 * Wd4];
        float4 hv;
        if (hOK) hv = sp[4 * Wd4];
        float bx0 = 0.f, bx1 = 0.f, bx2 = 0.f, bx3 = 0.f;
        if (fixB) {  // cross-wave w-boundary partner: scalar loads (4 thr/block)
            bx0 = ((const float*)(sp))[4];
            bx1 = ((const float*)(sp + Wd4))[4];
            bx2 = ((const float*)(sp + 2 * Wd4))[4];
            bx3 = ((const float*)(sp + 3 * Wd4))[4];
        }
        // w-boundary partner .x from lane+1 (same row, next float4)
        float s0 = __shfl_down(v0.x, 1, 64); if (fixB) s0 = bx0;
        float s1 = __shfl_down(v1.x, 1, 64); if (fixB) s1 = bx1;
        float s2 = __shfl_down(v2.x, 1, 64); if (fixB) s2 = bx2;
        float s3 = __shfl_down(v3.x, 1, 64); if (fixB) s3 = bx3;

        float dw;
        dw = v0.y - v0.x; aW[0] += dw * dw;
        dw = v0.z - v0.y; aW[1] += dw * dw;
        dw = v0.w - v0.z; aW[2] += dw * dw;
        dw = v1.y - v1.x; aW[0] += dw * dw;
        dw = v1.z - v1.y; aW[1] += dw * dw;
        dw = v1.w - v1.z; aW[2] += dw * dw;
        dw = v2.y - v2.x; aW[0] += dw * dw;
        dw = v2.z - v2.y; aW[1] += dw * dw;
        dw = v2.w - v2.z; aW[2] += dw * dw;
        dw = v3.y - v3.x; aW[0] += dw * dw;
        dw = v3.z - v3.y; aW[1] += dw * dw;
        dw = v3.w - v3.z; aW[2] += dw * dw;
        if (sOK) {
            dw = s0 - v0.w; aW[3] += dw * dw;
            dw = s1 - v1.w; aW[3] += dw * dw;
            dw = s2 - v2.w; aW[3] += dw * dw;
            dw = s3 - v3.w; aW[3] += dw * dw;
        }
        // h: 3 register-local pairs + 1 via hv
        aH[0] += sq4(v1, v0);
        aH[1] += sq4(v2, v1);
        aH[2] += sq4(v3, v2);
        if (hOK) aH[3] += sq4(hv, v3);
        // d: vs previous slice (rolling regs)
        if (it > 0)
            aD[it - 1] += sq4(v0, p0) + sq4(v1, p1) + sq4(v2, p2) + sq4(v3, p3);
        p0 = v0; p1 = v1; p2 = v2; p3 = v3;  // SSA under full unroll
    }
    if (!lastSeg) {  // halo slice d0+5: v-only, completes pair key d0+4
        const float4* sp = base + 5 * SLICE4;
        aD[4] = sq4(sp[0], p0) + sq4(sp[Wd4], p1) + sq4(sp[2 * Wd4], p2) + sq4(sp[3 * Wd4], p3);
    }

    // ---- flush (R6 LDS phases verbatim). Phase 1: H per-key scratch + D wave-reduce.
#pragma unroll
    for (int j = 0; j < 4; ++j) lds[(4 * rp + j) * 41 + c4] = aH[j];
#pragma unroll
    for (int j = 0; j < 5; ++j) {
        float dd = aD[j];
        for (int off = 32; off > 0; off >>= 1) dd += __shfl_down(dd, off, 64);
        if (lane == 0) lds[1472 + j * 5 + wv] = dd;
    }
    __syncthreads();
    float hsum = 0.f, dsum = 0.f;
    if (t < 32) {
        const float* src = &lds[t * 41];
        for (int i = 0; i < 40; ++i) hsum += src[i];
    }
    if (t < 5) {
        for (int w2 = 0; w2 < 5; ++w2) dsum += lds[1472 + t * 5 + w2];
    }
    __syncthreads();  // H region reads done; reuse for W
    // Phase 2: W per-key scratch (key 4c4+j, 8 contributors rp).
#pragma unroll
    for (int j = 0; j < 4; ++j) lds[(4 * c4 + j) * 9 + rp] = aW[j];
    __syncthreads();
    float wsum = 0.f;
    if (t < 160) {
        const float* src = &lds[t * 9];
        for (int i = 0; i < 8; ++i) wsum += src[i];
    }

    // ---- per-key device-scope accumulation (acc zeroed by zero_kernel).
    float* acc = ws;
    if (t < 5 && !(lastSeg && t == 4))          // D pair d0+t (159 pairs)
        atomicAdd(acc + (size_t)b * NPAIR + (d0 + t), dsum);
    if (t < 32 && !(hc == 4 && t == 31))        // H pair h0+t
        atomicAdd(acc + PBATCH + (size_t)b * NPAIR + (h0 + t), hsum);
    if (t < 159)                                // W pair t
        atomicAdd(acc + 2 * PBATCH + (size_t)b * NPAIR + t, wsum);

    // ---- last-block finish.
    __threadfence();
    if (t == 0) sTicket = atomicAdd((int*)(ws + NKEY), 1);
    __syncthreads();
    if (sTicket == NBLK - 1) {
        __threadfence();
        float part = 0.f;
        for (int gk = t; gk < NKEY; gk += 320) {
            const float val = __hip_atomic_load(acc + gk, __ATOMIC_RELAXED,
                                                __HIP_MEMORY_SCOPE_AGENT);
            const int a = gk / PBATCH;
            const float f = -0.5f * expf(-2.f * log_sigma[a]);  // -1/(2*sigma^2)
            part += expf(val * f);
        }
        for (int off = 32; off > 0; off >>= 1) part += __shfl_down(part, off, 64);
        __syncthreads();   // prior lds phases complete; reuse [0..4]
        if (lane == 0) lds[wv] = part;
        __syncthreads();
        if (t == 0) {
            const float tot = lds[0] + lds[1] + lds[2] + lds[3] + lds[4];
            out[0] = -tot / (float)NKEY;
        }
    }
}

extern "C" void kernel_launch(void* const* d_in, const int* in_sizes, int n_in,
                              void* d_out, int out_size, void* d_ws, size_t ws_size,
                              hipStream_t stream) {
    const float* x = (const float*)d_in[0];
    const float* log_sigma = (const float*)d_in[1];
    float* out = (float*)d_out;
    float* ws = (float*)d_ws;

    zero_kernel<<<1, 512, 0, stream>>>(ws);
    diff3_kernel<<<NBLK, 320, 0, stream>>>(x, log_sigma, ws, out);
}

// Round 7
// 196.954 us; speedup vs baseline: 1.5516x; 1.5516x over previous
//
#include <hip/hip_runtime.h>

// x: [8, 1, 160, 160, 160] fp32; log_sigma: [3] fp32; out: scalar fp32.
// loss = -(sum over 3816 (axis,b,pair) of exp(-sq/(2*sigma_axis^2))) / 3816.
//
// R13: R6 body + TRANSPOSED ws = coalesced tail. History:
//  - R10 probe: diff3 cold ~65-85us (read-side restructures R7/R9/R11 all
//    null -> ~2.9 TB/s cold-read is not source-schedulable). fill=75us fixed.
//  - R12: per-key device-scope atomics = catastrophe (diff3 185us; 250K
//    scattered cross-XCD atomic RMWs). REVERTED. Its accounting shows graph
//    gaps are small -> R6's remaining ~30-36us is the reduce/final tail.
//  - R6 tail cost: W-threads read 160 scalars at stride 800B (203K distinct
//    line requests from 3840 threads).
// Fix: contributor-major ws layout. diff3 writes Dt[hc][1272], Ht[ds][1272],
// Wt[r2][1272] — 5/32/159 CONSECUTIVE floats per block, every cell written
// exactly once (poison-safe, no zero kernel, no atomics in diff3). reduce:
// lanes read arr[ci*1272+rem] -> 256B contiguous per wave-iteration, ~814KB
// total. Per-key summation order identical to R6 (hc/ds/r2 ascending) ->
// bitwise-identical. final fused into reduce: 60 per-block atomicAdds to out
// (R11-validated; out zeroed by diff3, stream-ordered).
// Predicted: total 196 -> 165-178; absmax stays 0.0.

constexpr int Wd4 = 40;              // float4 per row
constexpr int SLICE4 = 6400;         // float4 per slice
constexpr long BSTR4 = 160L * 6400;  // float4 per batch
constexpr int NB = 8;
constexpr int NPAIR = 159;
constexpr int PBATCH = NB * NPAIR;     // 1272 keys per axis
constexpr int NKEY = 3 * PBATCH;       // 3816
constexpr int NBLK = NB * 160;         // 8 b x 32 d-segs x 5 h-chunks = 1280
constexpr int NRED = 60;               // 60*64 = 3840 >= 3816 keys
// ws float offsets (contributor-major): Dt[5][1272] @0, Ht[32][1272] @5*1272,
// Wt[160][1272] @37*1272. Total 197*1272 = 250,584 floats (~1 MB).
constexpr int HT_OFF = 5 * PBATCH;
constexpr int WT_OFF = 37 * PBATCH;

__device__ __forceinline__ float sq4(const float4& a, const float4& c) {
    float e0 = a.x - c.x, e1 = a.y - c.y, e2 = a.z - c.z, e3 = a.w - c.w;
    return e0 * e0 + e1 * e1 + e2 * e2 + e3 * e3;
}

// 1280 blocks x 320 threads. bid -> (b, ds 0..31, hc 0..4). Thread: c4=t%40,
// rp=t/40 owns rows h0+4rp+{0..3}. Slices d0..d0+4 owned, d0+5 halo (v only).
__global__ __launch_bounds__(320) void diff3_kernel(const float* __restrict__ x,
                                                    float* __restrict__ ws,
                                                    float* __restrict__ out) {
    __shared__ float lds[1504];  // H: [0..1311] 32 keys*41; D: [1472..1496]; W reuses [0..1439]

    const int t = threadIdx.x;
    const int bid = blockIdx.x;
    const int b = bid / 160;
    const int r2 = bid % 160;
    const int ds = r2 / 5;     // d-segment, d0 = 5*ds
    const int hc = r2 % 5;     // h-chunk,  h0 = 32*hc
    const int d0 = ds * 5, h0 = hc * 32;
    const bool lastSeg = (ds == 31);

    const int c4 = t % 40;
    const int rp = t / 40;                  // 0..7
    const int lane = t & 63;
    const int wv = t >> 6;                  // wave 0..4
    const bool hOK = !(hc == 4 && rp == 7); // row h0+4rp+4 <= 159
    const bool sOK = (c4 < 39);
    const bool fixB = (lane == 63) && sOK;  // shfl partner in next wave -> load

    if (bid == 0 && t == 0) out[0] = 0.f;   // reduce_kernel accumulates after us

    const float4* base = (const float4*)x + (size_t)b * BSTR4 + (size_t)d0 * SLICE4
                       + (size_t)(h0 + 4 * rp) * Wd4 + c4;

    float aW[4] = {0.f, 0.f, 0.f, 0.f};
    float aH[4] = {0.f, 0.f, 0.f, 0.f};
    float aD[5] = {0.f, 0.f, 0.f, 0.f, 0.f};
    float4 p0, p1, p2, p3;

#pragma unroll
    for (int it = 0; it < 5; ++it) {
        const float4* sp = base + it * SLICE4;
        const float4 v0 = sp[0];
        const float4 v1 = sp[Wd4];
        const float4 v2 = sp[2 * Wd4];
        const float4 v3 = sp[3 * Wd4];
        float4 hv;
        if (hOK) hv = sp[4 * Wd4];
        float bx0 = 0.f, bx1 = 0.f, bx2 = 0.f, bx3 = 0.f;
        if (fixB) {  // cross-wave w-boundary partner: scalar loads (4 thr/block)
            bx0 = ((const float*)(sp))[4];
            bx1 = ((const float*)(sp + Wd4))[4];
            bx2 = ((const float*)(sp + 2 * Wd4))[4];
            bx3 = ((const float*)(sp + 3 * Wd4))[4];
        }
        // w-boundary partner .x from lane+1 (same row, next float4)
        float s0 = __shfl_down(v0.x, 1, 64); if (fixB) s0 = bx0;
        float s1 = __shfl_down(v1.x, 1, 64); if (fixB) s1 = bx1;
        float s2 = __shfl_down(v2.x, 1, 64); if (fixB) s2 = bx2;
        float s3 = __shfl_down(v3.x, 1, 64); if (fixB) s3 = bx3;

        float dw;
        dw = v0.y - v0.x; aW[0] += dw * dw;
        dw = v0.z - v0.y; aW[1] += dw * dw;
        dw = v0.w - v0.z; aW[2] += dw * dw;
        dw = v1.y - v1.x; aW[0] += dw * dw;
        dw = v1.z - v1.y; aW[1] += dw * dw;
        dw = v1.w - v1.z; aW[2] += dw * dw;
        dw = v2.y - v2.x; aW[0] += dw * dw;
        dw = v2.z - v2.y; aW[1] += dw * dw;
        dw = v2.w - v2.z; aW[2] += dw * dw;
        dw = v3.y - v3.x; aW[0] += dw * dw;
        dw = v3.z - v3.y; aW[1] += dw * dw;
        dw = v3.w - v3.z; aW[2] += dw * dw;
        if (sOK) {
            dw = s0 - v0.w; aW[3] += dw * dw;
            dw = s1 - v1.w; aW[3] += dw * dw;
            dw = s2 - v2.w; aW[3] += dw * dw;
            dw = s3 - v3.w; aW[3] += dw * dw;
        }
        // h: 3 register-local pairs + 1 via hv
        aH[0] += sq4(v1, v0);
        aH[1] += sq4(v2, v1);
        aH[2] += sq4(v3, v2);
        if (hOK) aH[3] += sq4(hv, v3);
        // d: vs previous slice (rolling regs)
        if (it > 0)
            aD[it - 1] += sq4(v0, p0) + sq4(v1, p1) + sq4(v2, p2) + sq4(v3, p3);
        p0 = v0; p1 = v1; p2 = v2; p3 = v3;  // SSA under full unroll
    }
    if (!lastSeg) {  // halo slice d0+5: v-only, completes pair key d0+4
        const float4* sp = base + 5 * SLICE4;
        aD[4] = sq4(sp[0], p0) + sq4(sp[Wd4], p1) + sq4(sp[2 * Wd4], p2) + sq4(sp[3 * Wd4], p3);
    }

    // ---- flush (R6 LDS phases verbatim). Phase 1: H per-key scratch + D wave-reduce.
#pragma unroll
    for (int j = 0; j < 4; ++j) lds[(4 * rp + j) * 41 + c4] = aH[j];
#pragma unroll
    for (int j = 0; j < 5; ++j) {
        float dd = aD[j];
        for (int off = 32; off > 0; off >>= 1) dd += __shfl_down(dd, off, 64);
        if (lane == 0) lds[1472 + j * 5 + wv] = dd;
    }
    __syncthreads();
    float hsum = 0.f, dsum = 0.f;
    if (t < 32) {
        const float* src = &lds[t * 41];
        for (int i = 0; i < 40; ++i) hsum += src[i];
    }
    if (t < 5) {
        for (int w2 = 0; w2 < 5; ++w2) dsum += lds[1472 + t * 5 + w2];
    }
    __syncthreads();  // H region reads done; reuse for W
    // Phase 2: W per-key scratch (key 4c4+j, 8 contributors rp).
#pragma unroll
    for (int j = 0; j < 4; ++j) lds[(4 * c4 + j) * 9 + rp] = aW[j];
    __syncthreads();
    float wsum = 0.f;
    if (t < 160) {
        const float* src = &lds[t * 9];
        for (int i = 0; i < 8; ++i) wsum += src[i];
    }

    // ---- transposed, coalesced ws writes. Every cell written exactly once:
    // Dt[hc][b*159 + d0+t]   (t<5;  skip pair 159 at ds=31)
    // Ht[ds][b*159 + h0+t]   (t<32; skip pair 159 at hc=4)
    // Wt[r2][b*159 + t]      (t<159)
    const int kb = b * NPAIR;
    if (t < 5 && (d0 + t) < NPAIR)  ws[hc * PBATCH + kb + d0 + t] = dsum;
    if (t < 32 && (h0 + t) < NPAIR) ws[HT_OFF + ds * PBATCH + kb + h0 + t] = hsum;
    if (t < NPAIR)                  ws[WT_OFF + r2 * PBATCH + kb + t] = wsum;
}

// 60 blocks x 64 threads: one thread per (axis,b,pair). Contributor-major
// layout -> each loop iteration the wave reads 256B contiguous. Summation
// order per key identical to R6 (hc/ds/r2 ascending) -> bitwise-identical.
// final fused: one atomicAdd per block into out (zeroed by diff3).
__global__ __launch_bounds__(64) void reduce_kernel(const float* __restrict__ ws,
                                                    const float* __restrict__ log_sigma,
                                                    float* __restrict__ out) {
    const int gk = blockIdx.x * 64 + threadIdx.x;
    float kv = 0.f;
    if (gk < NKEY) {
        const int a = gk / PBATCH;
        const int rem = gk % PBATCH;   // b*159 + pair
        const float f = -0.5f * expf(-2.f * log_sigma[a]);  // -1/(2*sigma^2)
        float val = 0.f;
        if (a == 0) {
            for (int hc = 0; hc < 5; ++hc)   val += ws[hc * PBATCH + rem];
        } else if (a == 1) {
            for (int dss = 0; dss < 32; ++dss) val += ws[HT_OFF + dss * PBATCH + rem];
        } else {
            for (int ci = 0; ci < 160; ++ci) val += ws[WT_OFF + ci * PBATCH + rem];
        }
        kv = expf(val * f);
    }
    for (int off = 32; off > 0; off >>= 1) kv += __shfl_down(kv, off, 64);
    if (threadIdx.x == 0) atomicAdd(out, -kv / (float)NKEY);
}

extern "C" void kernel_launch(void* const* d_in, const int* in_sizes, int n_in,
                              void* d_out, int out_size, void* d_ws, size_t ws_size,
                              hipStream_t stream) {
    const float* x = (const float*)d_in[0];
    const float* log_sigma = (const float*)d_in[1];
    float* out = (float*)d_out;
    float* ws = (float*)d_ws;

    diff3_kernel<<<NBLK, 320, 0, stream>>>(x, ws, out);
    reduce_kernel<<<NRED, 64, 0, stream>>>(ws, log_sigma, out);
}